// Round 1
// baseline (67.213 us; speedup 1.0000x reference)
//
#include <hip/hip_runtime.h>
#include <math.h>

// x: (1,3,48,48,48) fp32, C-contiguous: idx = ((c*48 + d)*48 + h)*48 + w
// out[v] = sum(g*wd*p) / sum(g*wd) -- all normalizations cancel.
// wd = exp(-(p-c)^2 / (2*0.8^2)) = exp(-(p-c)^2 * 0.78125)
// g separable, sigma=1.1: G = {exp(-4/2.42), exp(-1/2.42), 1, exp(-1/2.42), exp(-4/2.42)}

__global__ __launch_bounds__(256)
void bilateral3d(const float* __restrict__ x, float* __restrict__ out,
                 float g0, float g1) {
    const int w0 = blockIdx.x * 16 + threadIdx.x;   // 0..47
    const int h0 = blockIdx.y * 16 + threadIdx.y;   // 0..47
    const int cd = blockIdx.z;                      // c*48 + d, 0..143
    const int d0 = cd % 48;

    const float G[5] = {g0, g1, 1.0f, g1, g0};

    const int center_idx = (cd * 48 + h0) * 48 + w0;
    const float center = x[center_idx];

    float num = 0.0f, den = 0.0f;

    for (int i = 0; i < 5; ++i) {
        int dd = d0 + i - 2;
        dd = dd < 0 ? 0 : (dd > 47 ? 47 : dd);
        const int dbase = (cd - d0 + dd) * 48;      // slice base (in rows)
        const float gi = G[i];
        #pragma unroll
        for (int j = 0; j < 5; ++j) {
            int hh = h0 + j - 2;
            hh = hh < 0 ? 0 : (hh > 47 ? 47 : hh);
            const float gij = gi * G[j];
            const float* __restrict__ row = x + (dbase + hh) * 48;
            #pragma unroll
            for (int l = 0; l < 5; ++l) {
                int ww = w0 + l - 2;
                ww = ww < 0 ? 0 : (ww > 47 ? 47 : ww);
                const float p = row[ww];
                const float dlt = p - center;
                const float wgt = gij * G[l] * __expf(dlt * dlt * -0.78125f);
                num = fmaf(wgt, p, num);
                den += wgt;
            }
        }
    }

    out[center_idx] = num / den;
}

extern "C" void kernel_launch(void* const* d_in, const int* in_sizes, int n_in,
                              void* d_out, int out_size, void* d_ws, size_t ws_size,
                              hipStream_t stream) {
    const float* x = (const float*)d_in[0];
    float* out = (float*)d_out;

    // gaussian 1D taps, sigma = 0.3*((5-1)/2 - 1) + 0.8 = 1.1; 2*sig^2 = 2.42
    const float g0 = expf(-4.0f / 2.42f);
    const float g1 = expf(-1.0f / 2.42f);

    dim3 block(16, 16, 1);
    dim3 grid(3, 3, 3 * 48);   // w-tiles, h-tiles, c*d slices
    hipLaunchKernelGGL(bilateral3d, grid, block, 0, stream, x, out, g0, g1);
}

// Round 2
// 64.150 us; speedup vs baseline: 1.0477x; 1.0477x over previous
//
#include <hip/hip_runtime.h>
#include <math.h>

// x: (1,3,48,48,48) fp32, C-contiguous: idx = (cd*48 + h)*48 + w, cd = c*48+d
// out[v] = sum(g*wd*p) / sum(g*wd) -- all normalizations cancel.
// wd*g folded into a single exp2: w = exp2(d^2 * C2 + LG[i]+LG[j]+LG[l])
//   C2   = -1/(2*0.8^2) * log2(e) = -0.78125 * 1.4426950408889634
//   LG[k]= log2(gauss tap k), sigma=1.1: LG = {L0, L1, 0, L1, L0}
//   L0 = -4/2.42*log2(e) = -2.3846116, L1 = L0/4 = -0.5961529

__global__ __launch_bounds__(256)
void bilateral3d(const float* __restrict__ x, float* __restrict__ out) {
    constexpr float C2 = -1.1271055f;
    constexpr float L0 = -2.3846116f;
    constexpr float L1 = -0.5961529f;
    constexpr float LG[5] = {L0, L1, 0.0f, L1, L0};

    const int w0 = blockIdx.x * 16 + threadIdx.x;   // 0..47
    const int h0 = blockIdx.y * 16 + threadIdx.y;   // 0..47
    const int cd = blockIdx.z;                      // c*48 + d
    const int d0 = cd % 48;
    const int dz = cd - d0;                         // c*48

    // hoisted clamped offsets (replicate pad)
    int dd[5], hh[5], ww[5];
    #pragma unroll
    for (int k = 0; k < 5; ++k) {
        int a = d0 + k - 2; dd[k] = a < 0 ? 0 : (a > 47 ? 47 : a);
        int b = h0 + k - 2; hh[k] = b < 0 ? 0 : (b > 47 ? 47 : b);
        int c = w0 + k - 2; ww[k] = c < 0 ? 0 : (c > 47 ? 47 : c);
    }

    // 25 precomputed row bases
    int rb[25];
    #pragma unroll
    for (int i = 0; i < 5; ++i)
        #pragma unroll
        for (int j = 0; j < 5; ++j)
            rb[i * 5 + j] = (dz + dd[i]) * 2304 + hh[j] * 48;

    const int center_idx = (cd * 48 + h0) * 48 + w0;
    const float center = x[center_idx];

    float num = 0.0f, den = 0.0f;

    #pragma unroll
    for (int i = 0; i < 5; ++i) {
        #pragma unroll
        for (int j = 0; j < 5; ++j) {
            const int base = rb[i * 5 + j];
            const float Lij = LG[i] + LG[j];        // compile-time constant
            #pragma unroll
            for (int l = 0; l < 5; ++l) {
                const float p = x[base + ww[l]];
                const float dlt = p - center;
                const float t = dlt * dlt;
                const float e = __builtin_amdgcn_exp2f(fmaf(t, C2, Lij + LG[l]));
                num = fmaf(e, p, num);
                den += e;
            }
        }
    }

    out[center_idx] = num / den;
}

extern "C" void kernel_launch(void* const* d_in, const int* in_sizes, int n_in,
                              void* d_out, int out_size, void* d_ws, size_t ws_size,
                              hipStream_t stream) {
    const float* x = (const float*)d_in[0];
    float* out = (float*)d_out;

    dim3 block(16, 16, 1);
    dim3 grid(3, 3, 3 * 48);   // w-tiles, h-tiles, c*d slices
    hipLaunchKernelGGL(bilateral3d, grid, block, 0, stream, x, out);
}